// Round 5
// baseline (336.405 us; speedup 1.0000x reference)
//
#include <hip/hip_runtime.h>

#define DEV_INLINE __device__ __forceinline__

static constexpr int KDIM = 128;
static constexpr int BUCKET_SHIFT = 8;           // 256 nodes per bucket
static constexpr int BUCKET_NODES = 1 << BUCKET_SHIFT;
static constexpr int CAP = 6144;                 // max edges per bucket (avg ~4096)
static constexpr int MAXNB = 512;                // max buckets supported

using s16x8 = __attribute__((ext_vector_type(8))) short;   // 8 bf16 (4 VGPR)
using f32x4 = __attribute__((ext_vector_type(4))) float;   // MFMA accumulator

// ---------------------------------------------------------------- helpers
DEV_INLINE float bf2f_lo(unsigned int u) {
    union { unsigned int u; float f; } c; c.u = u << 16; return c.f;
}
DEV_INLINE unsigned int f2bf(float f) {      // round-to-nearest-even
    union { float f; unsigned int u; } c; c.f = f;
    return (c.u + 0x7FFFu + ((c.u >> 16) & 1u)) >> 16;
}

DEV_INLINE void fma8(float w, const uint4& h, float* acc) {
    acc[0] = fmaf(w, bf2f_lo(h.x), acc[0]);
    acc[1] = fmaf(w, bf2f_lo(h.x >> 16), acc[1]);
    acc[2] = fmaf(w, bf2f_lo(h.y), acc[2]);
    acc[3] = fmaf(w, bf2f_lo(h.y >> 16), acc[3]);
    acc[4] = fmaf(w, bf2f_lo(h.z), acc[4]);
    acc[5] = fmaf(w, bf2f_lo(h.z >> 16), acc[5]);
    acc[6] = fmaf(w, bf2f_lo(h.w), acc[6]);
    acc[7] = fmaf(w, bf2f_lo(h.w >> 16), acc[7]);
}

// ---------------------------------------------------------------- bucketed CSR build
__global__ void k_zero(int* __restrict__ bucket_cursor, int nb) {
    int i = blockIdx.x * 256 + threadIdx.x;
    if (i < nb) bucket_cursor[i] = 0;
}

template <int EPT>
__global__ __launch_bounds__(256) void k_bin(
    const int* __restrict__ src, const int* __restrict__ dst,
    int* __restrict__ bucket_cursor, unsigned int* __restrict__ rec,
    int E, int NB) {
    __shared__ int hist[MAXNB];
    __shared__ int base[MAXNB];
    const int t = threadIdx.x;
    for (int i = t; i < NB; i += 256) hist[i] = 0;
    __syncthreads();

    const int e0 = blockIdx.x * (256 * EPT);
    int d[EPT], s[EPT];
#pragma unroll
    for (int i = 0; i < EPT; ++i) {
        int e = e0 + i * 256 + t;
        d[i] = (e < E) ? dst[e] : -1;
        s[i] = (e < E) ? src[e] : 0;
    }
#pragma unroll
    for (int i = 0; i < EPT; ++i)
        if (d[i] >= 0) atomicAdd(&hist[d[i] >> BUCKET_SHIFT], 1);
    __syncthreads();

    for (int i = t; i < NB; i += 256) {
        int h = hist[i];
        base[i] = (h > 0) ? atomicAdd(&bucket_cursor[i], h) : 0;
        hist[i] = 0;   // reuse as local rank cursor
    }
    __syncthreads();

#pragma unroll
    for (int i = 0; i < EPT; ++i) {
        if (d[i] >= 0) {
            int b = d[i] >> BUCKET_SHIFT;
            int r = atomicAdd(&hist[b], 1);
            unsigned int p = (unsigned int)s[i] |
                             ((unsigned int)(d[i] & (BUCKET_NODES - 1)) << 24);
            rec[(size_t)b * CAP + base[b] + r] = p;
        }
    }
}

__global__ __launch_bounds__(256) void k_degcsr(
    const int* __restrict__ bucket_cursor, const unsigned int* __restrict__ rec,
    int* __restrict__ csr_src, int* __restrict__ row_start, int* __restrict__ row_end,
    float* __restrict__ dinv, int N) {
    __shared__ int cnt[BUCKET_NODES];
    __shared__ int rstart[BUCKET_NODES];
    __shared__ int sc[BUCKET_NODES];
    const int b = blockIdx.x;
    const int t = threadIdx.x;
    const int node0 = b << BUCKET_SHIFT;
    const int ne = bucket_cursor[b];
    cnt[t] = 0;
    __syncthreads();

    const unsigned int* r0 = rec + (size_t)b * CAP;
    for (int j = t; j < ne; j += 256) atomicAdd(&cnt[r0[j] >> 24], 1);
    __syncthreads();

    int v = cnt[t];
    sc[t] = v;
    __syncthreads();
    for (int off = 1; off < 256; off <<= 1) {
        int add = (t >= off) ? sc[t - off] : 0;
        __syncthreads();
        sc[t] += add;
        __syncthreads();
    }
    int rs = sc[t] - v;  // exclusive
    rstart[t] = rs;
    if (node0 + t < N) {
        row_start[node0 + t] = b * CAP + rs;
        row_end[node0 + t]   = b * CAP + rs + v;
        dinv[node0 + t] = rsqrtf((float)v + 1.0f);  // +1 self-loop
    }
    cnt[t] = 0;  // reuse as rank cursor
    __syncthreads();

    for (int j = t; j < ne; j += 256) {
        unsigned int p = r0[j];
        int loc = p >> 24;
        int rk = atomicAdd(&cnt[loc], 1);
        csr_src[(size_t)b * CAP + rstart[loc] + rk] = (int)(p & 0x00FFFFFFu);
    }
}

// ---------------------------------------------------------------- W pre-swizzle into MFMA B-fragment order
// Wf layout: frag f = (variant*4 + kstep)*CT + ct ; ushort offset f*512 + lane*8 + j
// value = W[k][n], k = kstep*32 + (lane>>4)*8 + j, n = ct*16 + (lane&15)
__global__ void k_wprep(const float* __restrict__ W, unsigned short* __restrict__ Wf,
                        int NOUT) {
    const int tid = blockIdx.x * 256 + threadIdx.x;
    const int CT = NOUT >> 4;
    const int total = 8 * CT * 64;
    if (tid >= total) return;
    const int lane = tid & 63;
    const int f = tid >> 6;
    const int v = f / (4 * CT);
    const int r = f - v * 4 * CT;
    const int s = r / CT;
    const int ct = r - s * CT;
    const int k0 = s * 32 + ((lane >> 4) << 3);
    const int n = (ct << 4) + (lane & 15);
    unsigned int pk[4];
#pragma unroll
    for (int jp = 0; jp < 4; ++jp) {
        unsigned int h2[2];
#pragma unroll
        for (int e = 0; e < 2; ++e) {
            int j = jp * 2 + e;
            float w = W[(size_t)(k0 + j) * NOUT + n];
            unsigned int hb = f2bf(w);
            if (v) hb = f2bf(w - bf2f_lo(hb));
            h2[e] = hb;
        }
        pk[jp] = h2[0] | (h2[1] << 16);
    }
    reinterpret_cast<uint4*>(Wf)[tid] = make_uint4(pk[0], pk[1], pk[2], pk[3]);
}

// ---------------------------------------------------------------- MFMA GEMM  H = act(A) @ W
template <int NOUT, bool RELU_IN>
__global__ __launch_bounds__(256, 2) void k_mgemm(
    const float* __restrict__ A, const unsigned short* __restrict__ Wf,
    const float* __restrict__ bias, const float* __restrict__ dinv,
    unsigned short* __restrict__ Hs, float* __restrict__ OutInit, int N) {
    constexpr int CT = NOUT / 16;
    constexpr int U4 = CT * 512;
    __shared__ uint4 WfL[U4];
    for (int i = threadIdx.x; i < U4; i += 256)
        WfL[i] = reinterpret_cast<const uint4*>(Wf)[i];
    __syncthreads();

    const int lane = threadIdx.x & 63;
    const int kg = lane >> 4;
    const int lm = lane & 15;
    const int r0 = blockIdx.x * 64 + (threadIdx.x >> 6) * 16;
    const int arow = r0 + lm;

    s16x8 ah[4], al[4];
    const float4* A4 = reinterpret_cast<const float4*>(A);
#pragma unroll
    for (int s = 0; s < 4; ++s) {
        float4 p0 = make_float4(0.f, 0.f, 0.f, 0.f);
        float4 p1 = p0;
        if (arow < N) {
            p0 = A4[(size_t)arow * 32 + s * 8 + kg * 2];
            p1 = A4[(size_t)arow * 32 + s * 8 + kg * 2 + 1];
        }
        float vf[8] = {p0.x, p0.y, p0.z, p0.w, p1.x, p1.y, p1.z, p1.w};
#pragma unroll
        for (int j = 0; j < 8; ++j) {
            float w = RELU_IN ? fmaxf(vf[j], 0.f) : vf[j];
            unsigned int hb = f2bf(w);
            ah[s][j] = (short)hb;
            al[s][j] = (short)f2bf(w - bf2f_lo(hb));
        }
    }

    float dv[4];
#pragma unroll
    for (int q = 0; q < 4; ++q) {
        int orow = r0 + kg * 4 + q;
        dv[q] = (orow < N) ? dinv[orow] : 0.f;
    }

    const unsigned short* LW = reinterpret_cast<const unsigned short*>(WfL);
#pragma unroll
    for (int ct = 0; ct < CT; ++ct) {
        f32x4 acc = {0.f, 0.f, 0.f, 0.f};
#pragma unroll
        for (int s = 0; s < 4; ++s) {
            s16x8 bh = *reinterpret_cast<const s16x8*>(LW + ((size_t)(s * CT + ct)) * 512 + lane * 8);
            s16x8 bl = *reinterpret_cast<const s16x8*>(LW + ((size_t)((4 + s) * CT + ct)) * 512 + lane * 8);
            acc = __builtin_amdgcn_mfma_f32_16x16x32_bf16(ah[s], bh, acc, 0, 0, 0);
            acc = __builtin_amdgcn_mfma_f32_16x16x32_bf16(al[s], bh, acc, 0, 0, 0);
            acc = __builtin_amdgcn_mfma_f32_16x16x32_bf16(ah[s], bl, acc, 0, 0, 0);
        }
        const int col = ct * 16 + lm;
        const float bb = bias[col];
#pragma unroll
        for (int q = 0; q < 4; ++q) {
            int orow = r0 + kg * 4 + q;
            if (orow < N) {
                float h = acc[q];
                float di = dv[q];
                Hs[(size_t)orow * NOUT + col] = (unsigned short)f2bf(di * h);
                OutInit[(size_t)orow * NOUT + col] = fmaf(di * di, h, bb);
            }
        }
    }
}

// ---------------------------------------------------------------- fused gather1 + relu + GEMM2
__global__ __launch_bounds__(256, 4) void k_gconv2(
    const int* __restrict__ row_start, const int* __restrict__ row_end,
    const int* __restrict__ csr_src, const float* __restrict__ dinv,
    const unsigned short* __restrict__ hs1,   // [N][128] bf16, pre-scaled by dinv[src]
    const float* __restrict__ zp,             // [N][128] fp32 init (self-loop + bias)
    const unsigned short* __restrict__ Wf2,   // k_wprep(64) fragments
    const float* __restrict__ bias2,
    unsigned short* __restrict__ hs2,         // [N][64] bf16, pre-scaled (separate buffer!)
    float* __restrict__ outInit,              // [N][64] fp32
    int N) {
    __shared__ unsigned short AH[4 * 4 * 64 * 8];  // 16 KB hi fragments
    __shared__ unsigned short AL[4 * 4 * 64 * 8];  // 16 KB lo fragments
    const int t = threadIdx.x;
    const int nodeLocal = t >> 2;          // 0..63
    const int ks = t & 3;                  // k-slice (32 channels)
    const int node = blockIdx.x * 64 + nodeLocal;
    const int fw = nodeLocal >> 4;         // fragment wave
    const int flm = nodeLocal & 15;        // fragment row-in-tile

    float acc[32];
    if (node < N) {
        const float4* Z4 = reinterpret_cast<const float4*>(zp + (size_t)node * 128 + ks * 32);
#pragma unroll
        for (int i = 0; i < 8; ++i) {
            float4 v = Z4[i];
            acc[i * 4 + 0] = v.x; acc[i * 4 + 1] = v.y;
            acc[i * 4 + 2] = v.z; acc[i * 4 + 3] = v.w;
        }
        const int s0 = row_start[node];
        const int s1 = row_end[node];
        const float dn = dinv[node];
        const uint4* H = reinterpret_cast<const uint4*>(hs1);
        int j = s0;
        for (; j + 2 <= s1; j += 2) {
            int sa = csr_src[j];
            int sb = csr_src[j + 1];
            const uint4* Pa = H + (size_t)sa * 16 + ks * 4;
            const uint4* Pb = H + (size_t)sb * 16 + ks * 4;
            uint4 a0 = Pa[0], a1 = Pa[1], a2 = Pa[2], a3 = Pa[3];
            uint4 b0 = Pb[0], b1 = Pb[1], b2 = Pb[2], b3 = Pb[3];
            fma8(dn, a0, acc);      fma8(dn, a1, acc + 8);
            fma8(dn, a2, acc + 16); fma8(dn, a3, acc + 24);
            fma8(dn, b0, acc);      fma8(dn, b1, acc + 8);
            fma8(dn, b2, acc + 16); fma8(dn, b3, acc + 24);
        }
        if (j < s1) {
            int sa = csr_src[j];
            const uint4* Pa = H + (size_t)sa * 16 + ks * 4;
            uint4 a0 = Pa[0], a1 = Pa[1], a2 = Pa[2], a3 = Pa[3];
            fma8(dn, a0, acc);      fma8(dn, a1, acc + 8);
            fma8(dn, a2, acc + 16); fma8(dn, a3, acc + 24);
        }
    } else {
#pragma unroll
        for (int i = 0; i < 32; ++i) acc[i] = 0.f;
    }

    // relu + hi/lo split + fragment-linear LDS write
#pragma unroll
    for (int kg = 0; kg < 4; ++kg) {
        unsigned int hi[4], lo[4];
#pragma unroll
        for (int p = 0; p < 4; ++p) {
            float f0 = fmaxf(acc[kg * 8 + p * 2], 0.f);
            float f1 = fmaxf(acc[kg * 8 + p * 2 + 1], 0.f);
            unsigned int h0 = f2bf(f0), h1 = f2bf(f1);
            unsigned int l0 = f2bf(f0 - bf2f_lo(h0)), l1 = f2bf(f1 - bf2f_lo(h1));
            hi[p] = h0 | (h1 << 16);
            lo[p] = l0 | (l1 << 16);
        }
        const int idx = (((fw * 4 + ks) * 64) + kg * 16 + flm) * 8;  // ushort idx, 16B-aligned
        *reinterpret_cast<uint4*>(&AH[idx]) = make_uint4(hi[0], hi[1], hi[2], hi[3]);
        *reinterpret_cast<uint4*>(&AL[idx]) = make_uint4(lo[0], lo[1], lo[2], lo[3]);
    }
    __syncthreads();

    // phase 2: MFMA, 4 waves x 16 rows x 64 cols
    const int lane = t & 63;
    const int w2 = t >> 6;
    const int lm2 = lane & 15;
    const int kg4 = lane >> 4;
    const int r0 = blockIdx.x * 64 + w2 * 16;
    float dv[4];
#pragma unroll
    for (int q = 0; q < 4; ++q) {
        int orow = r0 + kg4 * 4 + q;
        dv[q] = (orow < N) ? dinv[orow] : 0.f;
    }
#pragma unroll
    for (int ct = 0; ct < 4; ++ct) {
        f32x4 c = {0.f, 0.f, 0.f, 0.f};
#pragma unroll
        for (int s = 0; s < 4; ++s) {
            s16x8 a_h = *reinterpret_cast<const s16x8*>(&AH[((w2 * 4 + s) * 64 + lane) * 8]);
            s16x8 a_l = *reinterpret_cast<const s16x8*>(&AL[((w2 * 4 + s) * 64 + lane) * 8]);
            s16x8 b_h = *reinterpret_cast<const s16x8*>(Wf2 + ((size_t)((s * 4 + ct) * 64 + lane)) * 8);
            s16x8 b_l = *reinterpret_cast<const s16x8*>(Wf2 + ((size_t)(((4 + s) * 4 + ct) * 64 + lane)) * 8);
            c = __builtin_amdgcn_mfma_f32_16x16x32_bf16(a_h, b_h, c, 0, 0, 0);
            c = __builtin_amdgcn_mfma_f32_16x16x32_bf16(a_l, b_h, c, 0, 0, 0);
            c = __builtin_amdgcn_mfma_f32_16x16x32_bf16(a_h, b_l, c, 0, 0, 0);
        }
        const int col = ct * 16 + lm2;
        const float bb = bias2[col];
#pragma unroll
        for (int q = 0; q < 4; ++q) {
            int orow = r0 + kg4 * 4 + q;
            if (orow < N) {
                float h = c[q];
                float di = dv[q];
                hs2[(size_t)orow * 64 + col] = (unsigned short)f2bf(di * h);
                outInit[(size_t)orow * 64 + col] = fmaf(di * di, h, bb);
            }
        }
    }
}

// ---------------------------------------------------------------- CSR gather-aggregate
template <int NOUT>
__global__ void k_gather(const int* __restrict__ row_start, const int* __restrict__ row_end,
                         const int* __restrict__ csr_src,
                         const float* __restrict__ dinv,
                         const unsigned short* __restrict__ Hs,
                         float* __restrict__ Acc, int N) {
    constexpr int LPG = NOUT / 8;
    const int lane = threadIdx.x % LPG;
    const int node = blockIdx.x * (256 / LPG) + threadIdx.x / LPG;
    if (node >= N) return;
    const int s0 = row_start[node];
    const int s1 = row_end[node];
    if (s0 == s1) return;
    const float dn = dinv[node];
    const uint4* H8 = reinterpret_cast<const uint4*>(Hs);
    float acc[8];
#pragma unroll
    for (int i = 0; i < 8; ++i) acc[i] = 0.f;

    int j = s0;
    for (; j + 2 <= s1; j += 2) {
        int sa = csr_src[j];
        int sb = csr_src[j + 1];
        uint4 ha = H8[(size_t)sa * LPG + lane];
        uint4 hb = H8[(size_t)sb * LPG + lane];
        fma8(dn, ha, acc);
        fma8(dn, hb, acc);
    }
    if (j < s1) {
        int sa = csr_src[j];
        uint4 ha = H8[(size_t)sa * LPG + lane];
        fma8(dn, ha, acc);
    }

    float4* O4 = reinterpret_cast<float4*>(Acc + (size_t)node * NOUT + lane * 8);
    float4 o0 = O4[0], o1 = O4[1];
    o0.x += acc[0]; o0.y += acc[1]; o0.z += acc[2]; o0.w += acc[3];
    o1.x += acc[4]; o1.y += acc[5]; o1.z += acc[6]; o1.w += acc[7];
    O4[0] = o0; O4[1] = o1;
}

// ---------------------------------------------------------------- launch
extern "C" void kernel_launch(void* const* d_in, const int* in_sizes, int n_in,
                              void* d_out, int out_size, void* d_ws, size_t ws_size,
                              hipStream_t stream) {
    const float* x  = (const float*)d_in[0];
    const int*   ei = (const int*)d_in[1];
    const float* W1 = (const float*)d_in[2];
    const float* b1 = (const float*)d_in[3];
    const float* W2 = (const float*)d_in[4];
    const float* b2 = (const float*)d_in[5];
    float* out = (float*)d_out;

    const int N = in_sizes[0] / 128;
    const int E = in_sizes[1] / 2;
    const int* src = ei;       // edge_index[0]
    const int* dst = ei + E;   // edge_index[1]
    const int NB = (N + BUCKET_NODES - 1) >> BUCKET_SHIFT;

    char* ws = (char*)d_ws;
    size_t off = 0;
    auto alloc = [&](size_t bytes) -> char* {
        char* p = ws + off;
        off += (bytes + 255) & ~size_t(255);
        return p;
    };
    int*            bucket_cursor = (int*)alloc((size_t)MAXNB * 4);
    int*            row_start     = (int*)alloc((size_t)N * 4);
    int*            row_end       = (int*)alloc((size_t)N * 4);
    float*          dinv          = (float*)alloc((size_t)N * 4);
    unsigned int*   rec           = (unsigned int*)alloc((size_t)NB * CAP * 4);
    int*            csr_src       = (int*)alloc((size_t)NB * CAP * 4);
    unsigned short* hs1           = (unsigned short*)alloc((size_t)N * 128 * 2);
    unsigned short* hs2           = (unsigned short*)alloc((size_t)N * 64 * 2);
    float*          zp            = (float*)alloc((size_t)N * 128 * 4);
    unsigned short* wf1           = (unsigned short*)alloc(128 * 128 * 2 * 2);  // 64 KB
    unsigned short* wf2           = (unsigned short*)alloc(128 * 64 * 2 * 2);   // 32 KB
    (void)ws_size; (void)n_in; (void)out_size;

    constexpr int EPT = 8;
    const int bin_blocks = (E + 256 * EPT - 1) / (256 * EPT);

    hipLaunchKernelGGL(k_zero, dim3((NB + 255) / 256), dim3(256), 0, stream,
                       bucket_cursor, NB);
    hipLaunchKernelGGL(k_wprep, dim3(16), dim3(256), 0, stream, W1, wf1, 128);
    hipLaunchKernelGGL(k_wprep, dim3(8), dim3(256), 0, stream, W2, wf2, 64);
    hipLaunchKernelGGL((k_bin<EPT>), dim3(bin_blocks), dim3(256), 0, stream,
                       src, dst, bucket_cursor, rec, E, NB);
    hipLaunchKernelGGL(k_degcsr, dim3(NB), dim3(256), 0, stream,
                       bucket_cursor, rec, csr_src, row_start, row_end, dinv, N);

    // conv1 GEMM: hs1 = bf16(dinv*x@W1) ; zp = dinv^2*(x@W1) + b1
    hipLaunchKernelGGL((k_mgemm<128, false>), dim3((N + 63) / 64), dim3(256), 0, stream,
                       x, wf1, b1, dinv, hs1, zp, N);

    // fused: gather1 + relu + GEMM2 -> hs2 + out-init
    hipLaunchKernelGGL(k_gconv2, dim3((N + 63) / 64), dim3(256), 0, stream,
                       row_start, row_end, csr_src, dinv, hs1, zp, wf2, b2,
                       hs2, out, N);

    // conv2 aggregate: out += dinv * sum(hs2[src])
    hipLaunchKernelGGL((k_gather<64>), dim3((N + 31) / 32), dim3(256), 0, stream,
                       row_start, row_end, csr_src, dinv, hs2, out, N);
}

// Round 6
// 298.586 us; speedup vs baseline: 1.1267x; 1.1267x over previous
//
#include <hip/hip_runtime.h>

#define DEV_INLINE __device__ __forceinline__

static constexpr int KDIM = 128;
static constexpr int BUCKET_SHIFT = 8;           // 256 nodes per bucket
static constexpr int BUCKET_NODES = 1 << BUCKET_SHIFT;
static constexpr int CAP = 6144;                 // max edges per bucket (avg ~4096)
static constexpr int MAXNB = 512;                // max buckets supported

using s16x8 = __attribute__((ext_vector_type(8))) short;   // 8 bf16 (4 VGPR)
using f32x4 = __attribute__((ext_vector_type(4))) float;   // MFMA accumulator

// ---------------------------------------------------------------- helpers
DEV_INLINE float bf2f_lo(unsigned int u) {
    union { unsigned int u; float f; } c; c.u = u << 16; return c.f;
}
DEV_INLINE unsigned int f2bf(float f) {      // round-to-nearest-even
    union { float f; unsigned int u; } c; c.f = f;
    return (c.u + 0x7FFFu + ((c.u >> 16) & 1u)) >> 16;
}

DEV_INLINE void fma8(float w, const uint4& h, float* acc) {
    acc[0] = fmaf(w, bf2f_lo(h.x), acc[0]);
    acc[1] = fmaf(w, bf2f_lo(h.x >> 16), acc[1]);
    acc[2] = fmaf(w, bf2f_lo(h.y), acc[2]);
    acc[3] = fmaf(w, bf2f_lo(h.y >> 16), acc[3]);
    acc[4] = fmaf(w, bf2f_lo(h.z), acc[4]);
    acc[5] = fmaf(w, bf2f_lo(h.z >> 16), acc[5]);
    acc[6] = fmaf(w, bf2f_lo(h.w), acc[6]);
    acc[7] = fmaf(w, bf2f_lo(h.w >> 16), acc[7]);
}

// ---------------------------------------------------------------- bucketed CSR build
__global__ void k_zero(int* __restrict__ bucket_cursor, int nb) {
    int i = blockIdx.x * 256 + threadIdx.x;
    if (i < nb) bucket_cursor[i] = 0;
}

template <int EPT>
__global__ __launch_bounds__(256) void k_bin(
    const int* __restrict__ src, const int* __restrict__ dst,
    int* __restrict__ bucket_cursor, unsigned int* __restrict__ rec,
    int E, int NB) {
    __shared__ int hist[MAXNB];
    __shared__ int base[MAXNB];
    const int t = threadIdx.x;
    for (int i = t; i < NB; i += 256) hist[i] = 0;
    __syncthreads();

    const int e0 = blockIdx.x * (256 * EPT);
    int d[EPT], s[EPT];
#pragma unroll
    for (int i = 0; i < EPT; ++i) {
        int e = e0 + i * 256 + t;
        d[i] = (e < E) ? dst[e] : -1;
        s[i] = (e < E) ? src[e] : 0;
    }
#pragma unroll
    for (int i = 0; i < EPT; ++i)
        if (d[i] >= 0) atomicAdd(&hist[d[i] >> BUCKET_SHIFT], 1);
    __syncthreads();

    for (int i = t; i < NB; i += 256) {
        int h = hist[i];
        base[i] = (h > 0) ? atomicAdd(&bucket_cursor[i], h) : 0;
        hist[i] = 0;   // reuse as local rank cursor
    }
    __syncthreads();

#pragma unroll
    for (int i = 0; i < EPT; ++i) {
        if (d[i] >= 0) {
            int b = d[i] >> BUCKET_SHIFT;
            int r = atomicAdd(&hist[b], 1);
            unsigned int p = (unsigned int)s[i] |
                             ((unsigned int)(d[i] & (BUCKET_NODES - 1)) << 24);
            rec[(size_t)b * CAP + base[b] + r] = p;
        }
    }
}

__global__ __launch_bounds__(256) void k_degcsr(
    const int* __restrict__ bucket_cursor, const unsigned int* __restrict__ rec,
    int* __restrict__ csr_src, int* __restrict__ row_start, int* __restrict__ row_end,
    float* __restrict__ dinv, int N) {
    __shared__ int cnt[BUCKET_NODES];
    __shared__ int rstart[BUCKET_NODES];
    __shared__ int sc[BUCKET_NODES];
    const int b = blockIdx.x;
    const int t = threadIdx.x;
    const int node0 = b << BUCKET_SHIFT;
    const int ne = bucket_cursor[b];
    cnt[t] = 0;
    __syncthreads();

    const unsigned int* r0 = rec + (size_t)b * CAP;
    for (int j = t; j < ne; j += 256) atomicAdd(&cnt[r0[j] >> 24], 1);
    __syncthreads();

    int v = cnt[t];
    sc[t] = v;
    __syncthreads();
    for (int off = 1; off < 256; off <<= 1) {
        int add = (t >= off) ? sc[t - off] : 0;
        __syncthreads();
        sc[t] += add;
        __syncthreads();
    }
    int rs = sc[t] - v;  // exclusive
    rstart[t] = rs;
    if (node0 + t < N) {
        row_start[node0 + t] = b * CAP + rs;
        row_end[node0 + t]   = b * CAP + rs + v;
        dinv[node0 + t] = rsqrtf((float)v + 1.0f);  // +1 self-loop
    }
    cnt[t] = 0;  // reuse as rank cursor
    __syncthreads();

    for (int j = t; j < ne; j += 256) {
        unsigned int p = r0[j];
        int loc = p >> 24;
        int rk = atomicAdd(&cnt[loc], 1);
        csr_src[(size_t)b * CAP + rstart[loc] + rk] = (int)(p & 0x00FFFFFFu);
    }
}

// ---------------------------------------------------------------- W pre-swizzle into MFMA B-fragment order
// Wf layout: frag f = (variant*4 + kstep)*CT + ct ; ushort offset f*512 + lane*8 + j
// value = W[k][n], k = kstep*32 + (lane>>4)*8 + j, n = ct*16 + (lane&15)
__global__ void k_wprep(const float* __restrict__ W, unsigned short* __restrict__ Wf,
                        int NOUT) {
    const int tid = blockIdx.x * 256 + threadIdx.x;
    const int CT = NOUT >> 4;
    const int total = 8 * CT * 64;
    if (tid >= total) return;
    const int lane = tid & 63;
    const int f = tid >> 6;
    const int v = f / (4 * CT);
    const int r = f - v * 4 * CT;
    const int s = r / CT;
    const int ct = r - s * CT;
    const int k0 = s * 32 + ((lane >> 4) << 3);
    const int n = (ct << 4) + (lane & 15);
    unsigned int pk[4];
#pragma unroll
    for (int jp = 0; jp < 4; ++jp) {
        unsigned int h2[2];
#pragma unroll
        for (int e = 0; e < 2; ++e) {
            int j = jp * 2 + e;
            float w = W[(size_t)(k0 + j) * NOUT + n];
            unsigned int hb = f2bf(w);
            if (v) hb = f2bf(w - bf2f_lo(hb));
            h2[e] = hb;
        }
        pk[jp] = h2[0] | (h2[1] << 16);
    }
    reinterpret_cast<uint4*>(Wf)[tid] = make_uint4(pk[0], pk[1], pk[2], pk[3]);
}

// ---------------------------------------------------------------- MFMA GEMM  Hs = bf16(dinv * act(A)@W)
// 3-term bf16 split (hi*hi + lo*hi + hi*lo) == fp32 accuracy to ~2^-18.
// Writes ONLY the pre-scaled bf16 table; the self-loop/bias term is
// reconstructed inside the gather from this same table.
template <int NOUT, bool RELU_IN>
__global__ __launch_bounds__(256, 2) void k_mgemm(
    const float* __restrict__ A, const unsigned short* __restrict__ Wf,
    const float* __restrict__ dinv,
    unsigned short* __restrict__ Hs, int N) {
    constexpr int CT = NOUT / 16;
    constexpr int U4 = CT * 512;
    __shared__ uint4 WfL[U4];
    for (int i = threadIdx.x; i < U4; i += 256)
        WfL[i] = reinterpret_cast<const uint4*>(Wf)[i];
    __syncthreads();

    const int lane = threadIdx.x & 63;
    const int kg = lane >> 4;
    const int lm = lane & 15;
    const int r0 = blockIdx.x * 64 + (threadIdx.x >> 6) * 16;
    const int arow = r0 + lm;

    s16x8 ah[4], al[4];
    const float4* A4 = reinterpret_cast<const float4*>(A);
#pragma unroll
    for (int s = 0; s < 4; ++s) {
        float4 p0 = make_float4(0.f, 0.f, 0.f, 0.f);
        float4 p1 = p0;
        if (arow < N) {
            p0 = A4[(size_t)arow * 32 + s * 8 + kg * 2];
            p1 = A4[(size_t)arow * 32 + s * 8 + kg * 2 + 1];
        }
        float vf[8] = {p0.x, p0.y, p0.z, p0.w, p1.x, p1.y, p1.z, p1.w};
#pragma unroll
        for (int j = 0; j < 8; ++j) {
            float w = RELU_IN ? fmaxf(vf[j], 0.f) : vf[j];
            unsigned int hb = f2bf(w);
            ah[s][j] = (short)hb;
            al[s][j] = (short)f2bf(w - bf2f_lo(hb));
        }
    }

    float dv[4];
#pragma unroll
    for (int q = 0; q < 4; ++q) {
        int orow = r0 + kg * 4 + q;
        dv[q] = (orow < N) ? dinv[orow] : 0.f;
    }

    const unsigned short* LW = reinterpret_cast<const unsigned short*>(WfL);
#pragma unroll
    for (int ct = 0; ct < CT; ++ct) {
        f32x4 acc = {0.f, 0.f, 0.f, 0.f};
#pragma unroll
        for (int s = 0; s < 4; ++s) {
            s16x8 bh = *reinterpret_cast<const s16x8*>(LW + ((size_t)(s * CT + ct)) * 512 + lane * 8);
            s16x8 bl = *reinterpret_cast<const s16x8*>(LW + ((size_t)((4 + s) * CT + ct)) * 512 + lane * 8);
            acc = __builtin_amdgcn_mfma_f32_16x16x32_bf16(ah[s], bh, acc, 0, 0, 0);
            acc = __builtin_amdgcn_mfma_f32_16x16x32_bf16(al[s], bh, acc, 0, 0, 0);
            acc = __builtin_amdgcn_mfma_f32_16x16x32_bf16(ah[s], bl, acc, 0, 0, 0);
        }
        const int col = ct * 16 + lm;
#pragma unroll
        for (int q = 0; q < 4; ++q) {
            int orow = r0 + kg * 4 + q;
            if (orow < N)
                Hs[(size_t)orow * NOUT + col] = (unsigned short)f2bf(dv[q] * acc[q]);
        }
    }
}

// ---------------------------------------------------------------- CSR gather-aggregate (full write, no RMW)
// Out[node] = dinv[node] * ( sum_j Hs[src_j] + Hs[node] ) + bias
//   (Hs pre-scaled by dinv of the row owner; Hs[node] reconstructs the
//    self-loop term dinv^2*h to bf16 accuracy.)
template <int NOUT>
__global__ void k_gather(const int* __restrict__ row_start, const int* __restrict__ row_end,
                         const int* __restrict__ csr_src,
                         const float* __restrict__ dinv,
                         const unsigned short* __restrict__ Hs,
                         const float* __restrict__ bias,
                         float* __restrict__ Out, int N) {
    constexpr int LPG = NOUT / 8;
    const int lane = threadIdx.x % LPG;
    const int node = blockIdx.x * (256 / LPG) + threadIdx.x / LPG;
    if (node >= N) return;
    const int s0 = row_start[node];
    const int s1 = row_end[node];
    const float dn = dinv[node];
    const uint4* H8 = reinterpret_cast<const uint4*>(Hs);
    float acc[8];
#pragma unroll
    for (int i = 0; i < 8; ++i) acc[i] = 0.f;

    int j = s0;
    for (; j + 2 <= s1; j += 2) {
        int sa = csr_src[j];
        int sb = csr_src[j + 1];
        uint4 ha = H8[(size_t)sa * LPG + lane];
        uint4 hb = H8[(size_t)sb * LPG + lane];
        fma8(dn, ha, acc);
        fma8(dn, hb, acc);
    }
    if (j < s1) {
        int sa = csr_src[j];
        uint4 ha = H8[(size_t)sa * LPG + lane];
        fma8(dn, ha, acc);
    }
    // self-loop term from own row of the table
    {
        uint4 hv = H8[(size_t)node * LPG + lane];
        fma8(dn, hv, acc);
    }

    const float4* B4 = reinterpret_cast<const float4*>(bias + lane * 8);
    float4 b0 = B4[0], b1 = B4[1];
    float4 o0, o1;
    o0.x = acc[0] + b0.x; o0.y = acc[1] + b0.y; o0.z = acc[2] + b0.z; o0.w = acc[3] + b0.w;
    o1.x = acc[4] + b1.x; o1.y = acc[5] + b1.y; o1.z = acc[6] + b1.z; o1.w = acc[7] + b1.w;
    float4* O4 = reinterpret_cast<float4*>(Out + (size_t)node * NOUT + lane * 8);
    O4[0] = o0; O4[1] = o1;
}

// ---------------------------------------------------------------- launch
extern "C" void kernel_launch(void* const* d_in, const int* in_sizes, int n_in,
                              void* d_out, int out_size, void* d_ws, size_t ws_size,
                              hipStream_t stream) {
    const float* x  = (const float*)d_in[0];
    const int*   ei = (const int*)d_in[1];
    const float* W1 = (const float*)d_in[2];
    const float* b1 = (const float*)d_in[3];
    const float* W2 = (const float*)d_in[4];
    const float* b2 = (const float*)d_in[5];
    float* out = (float*)d_out;

    const int N = in_sizes[0] / 128;
    const int E = in_sizes[1] / 2;
    const int* src = ei;       // edge_index[0]
    const int* dst = ei + E;   // edge_index[1]
    const int NB = (N + BUCKET_NODES - 1) >> BUCKET_SHIFT;

    char* ws = (char*)d_ws;
    size_t off = 0;
    auto alloc = [&](size_t bytes) -> char* {
        char* p = ws + off;
        off += (bytes + 255) & ~size_t(255);
        return p;
    };
    int*            bucket_cursor = (int*)alloc((size_t)MAXNB * 4);
    int*            row_start     = (int*)alloc((size_t)N * 4);
    int*            row_end       = (int*)alloc((size_t)N * 4);
    float*          dinv          = (float*)alloc((size_t)N * 4);
    unsigned int*   rec           = (unsigned int*)alloc((size_t)NB * CAP * 4);
    int*            csr_src       = (int*)alloc((size_t)NB * CAP * 4);
    unsigned short* hs1           = (unsigned short*)alloc((size_t)N * 128 * 2);
    unsigned short* hs2           = (unsigned short*)alloc((size_t)N * 64 * 2);
    float*          zp            = (float*)alloc((size_t)N * 128 * 4);
    unsigned short* wf1           = (unsigned short*)alloc(128 * 128 * 2 * 2);  // 64 KB
    unsigned short* wf2           = (unsigned short*)alloc(128 * 64 * 2 * 2);   // 32 KB
    (void)ws_size; (void)n_in; (void)out_size;

    constexpr int EPT = 8;
    const int bin_blocks = (E + 256 * EPT - 1) / (256 * EPT);

    hipLaunchKernelGGL(k_zero, dim3((NB + 255) / 256), dim3(256), 0, stream,
                       bucket_cursor, NB);
    hipLaunchKernelGGL(k_wprep, dim3(16), dim3(256), 0, stream, W1, wf1, 128);
    hipLaunchKernelGGL(k_wprep, dim3(8), dim3(256), 0, stream, W2, wf2, 64);
    hipLaunchKernelGGL((k_bin<EPT>), dim3(bin_blocks), dim3(256), 0, stream,
                       src, dst, bucket_cursor, rec, E, NB);
    hipLaunchKernelGGL(k_degcsr, dim3(NB), dim3(256), 0, stream,
                       bucket_cursor, rec, csr_src, row_start, row_end, dinv, N);

    // conv1 GEMM: hs1 = bf16(dinv * x@W1)
    hipLaunchKernelGGL((k_mgemm<128, false>), dim3((N + 63) / 64), dim3(256), 0, stream,
                       x, wf1, dinv, hs1, N);

    // conv1 aggregate (writes zp fully: msgs + self + b1)
    hipLaunchKernelGGL((k_gather<128>), dim3((N + 15) / 16), dim3(256), 0, stream,
                       row_start, row_end, csr_src, dinv, hs1, b1, zp, N);

    // conv2 GEMM: hs2 = bf16(dinv * relu(zp)@W2)
    hipLaunchKernelGGL((k_mgemm<64, true>), dim3((N + 63) / 64), dim3(256), 0, stream,
                       zp, wf2, dinv, hs2, N);

    // conv2 aggregate (writes out fully: msgs + self + b2)
    hipLaunchKernelGGL((k_gather<64>), dim3((N + 31) / 32), dim3(256), 0, stream,
                       row_start, row_end, csr_src, dinv, hs2, b2, out, N);
}

// Round 7
// 262.180 us; speedup vs baseline: 1.2831x; 1.1389x over previous
//
#include <hip/hip_runtime.h>

#define DEV_INLINE __device__ __forceinline__

static constexpr int KDIM = 128;
static constexpr int BUCKET_SHIFT = 8;           // 256 nodes per bucket
static constexpr int BUCKET_NODES = 1 << BUCKET_SHIFT;
static constexpr int CAP = 6144;                 // max edges per bucket (avg ~4096)
static constexpr int MAXNB = 512;                // max buckets supported

using s16x8 = __attribute__((ext_vector_type(8))) short;   // 8 bf16 (4 VGPR)
using f32x4 = __attribute__((ext_vector_type(4))) float;   // MFMA accumulator
using f32x2 = __attribute__((ext_vector_type(2))) float;

// ---------------------------------------------------------------- helpers
DEV_INLINE float bf2f_lo(unsigned int u) {
    union { unsigned int u; float f; } c; c.u = u << 16; return c.f;
}
DEV_INLINE unsigned int f2bf(float f) {      // round-to-nearest-even
    union { float f; unsigned int u; } c; c.f = f;
    return (c.u + 0x7FFFu + ((c.u >> 16) & 1u)) >> 16;
}

DEV_INLINE void fma8(float w, const uint4& h, float* acc) {   // 8 bf16
    acc[0] = fmaf(w, bf2f_lo(h.x), acc[0]);
    acc[1] = fmaf(w, bf2f_lo(h.x >> 16), acc[1]);
    acc[2] = fmaf(w, bf2f_lo(h.y), acc[2]);
    acc[3] = fmaf(w, bf2f_lo(h.y >> 16), acc[3]);
    acc[4] = fmaf(w, bf2f_lo(h.z), acc[4]);
    acc[5] = fmaf(w, bf2f_lo(h.z >> 16), acc[5]);
    acc[6] = fmaf(w, bf2f_lo(h.w), acc[6]);
    acc[7] = fmaf(w, bf2f_lo(h.w >> 16), acc[7]);
}

DEV_INLINE void fma4fp8(float w, unsigned int u, float* acc) {  // 4 fp8 e4m3
    f32x2 p;
    p = __builtin_amdgcn_cvt_pk_f32_fp8((int)u, false);
    acc[0] = fmaf(w, p[0], acc[0]);
    acc[1] = fmaf(w, p[1], acc[1]);
    p = __builtin_amdgcn_cvt_pk_f32_fp8((int)u, true);
    acc[2] = fmaf(w, p[0], acc[2]);
    acc[3] = fmaf(w, p[1], acc[3]);
}
DEV_INLINE void fma16fp8(float w, const uint4& h, float* acc) { // 16 fp8
    fma4fp8(w, h.x, acc);
    fma4fp8(w, h.y, acc + 4);
    fma4fp8(w, h.z, acc + 8);
    fma4fp8(w, h.w, acc + 12);
}

DEV_INLINE unsigned char f2fp8(float f) {
    return (unsigned char)(__builtin_amdgcn_cvt_pk_fp8_f32(f, f, 0, false) & 0xFF);
}

// ---------------------------------------------------------------- bucketed CSR build
__global__ void k_zero(int* __restrict__ bucket_cursor, int nb) {
    int i = blockIdx.x * 256 + threadIdx.x;
    if (i < nb) bucket_cursor[i] = 0;
}

template <int EPT>
__global__ __launch_bounds__(256) void k_bin(
    const int* __restrict__ src, const int* __restrict__ dst,
    int* __restrict__ bucket_cursor, unsigned int* __restrict__ rec,
    int E, int NB) {
    __shared__ int hist[MAXNB];
    __shared__ int base[MAXNB];
    const int t = threadIdx.x;
    for (int i = t; i < NB; i += 256) hist[i] = 0;
    __syncthreads();

    const int e0 = blockIdx.x * (256 * EPT);
    int d[EPT], s[EPT];
#pragma unroll
    for (int i = 0; i < EPT; ++i) {
        int e = e0 + i * 256 + t;
        d[i] = (e < E) ? dst[e] : -1;
        s[i] = (e < E) ? src[e] : 0;
    }
#pragma unroll
    for (int i = 0; i < EPT; ++i)
        if (d[i] >= 0) atomicAdd(&hist[d[i] >> BUCKET_SHIFT], 1);
    __syncthreads();

    for (int i = t; i < NB; i += 256) {
        int h = hist[i];
        base[i] = (h > 0) ? atomicAdd(&bucket_cursor[i], h) : 0;
        hist[i] = 0;   // reuse as local rank cursor
    }
    __syncthreads();

#pragma unroll
    for (int i = 0; i < EPT; ++i) {
        if (d[i] >= 0) {
            int b = d[i] >> BUCKET_SHIFT;
            int r = atomicAdd(&hist[b], 1);
            unsigned int p = (unsigned int)s[i] |
                             ((unsigned int)(d[i] & (BUCKET_NODES - 1)) << 24);
            rec[(size_t)b * CAP + base[b] + r] = p;
        }
    }
}

__global__ __launch_bounds__(256) void k_degcsr(
    const int* __restrict__ bucket_cursor, const unsigned int* __restrict__ rec,
    int* __restrict__ csr_src, int* __restrict__ row_start, int* __restrict__ row_end,
    float* __restrict__ dinv, int N) {
    __shared__ int cnt[BUCKET_NODES];
    __shared__ int rstart[BUCKET_NODES];
    __shared__ int sc[BUCKET_NODES];
    const int b = blockIdx.x;
    const int t = threadIdx.x;
    const int node0 = b << BUCKET_SHIFT;
    const int ne = bucket_cursor[b];
    cnt[t] = 0;
    __syncthreads();

    const unsigned int* r0 = rec + (size_t)b * CAP;
    for (int j = t; j < ne; j += 256) atomicAdd(&cnt[r0[j] >> 24], 1);
    __syncthreads();

    int v = cnt[t];
    sc[t] = v;
    __syncthreads();
    for (int off = 1; off < 256; off <<= 1) {
        int add = (t >= off) ? sc[t - off] : 0;
        __syncthreads();
        sc[t] += add;
        __syncthreads();
    }
    int rs = sc[t] - v;  // exclusive
    rstart[t] = rs;
    if (node0 + t < N) {
        row_start[node0 + t] = b * CAP + rs;
        row_end[node0 + t]   = b * CAP + rs + v;
        dinv[node0 + t] = rsqrtf((float)v + 1.0f);  // +1 self-loop
    }
    cnt[t] = 0;  // reuse as rank cursor
    __syncthreads();

    for (int j = t; j < ne; j += 256) {
        unsigned int p = r0[j];
        int loc = p >> 24;
        int rk = atomicAdd(&cnt[loc], 1);
        csr_src[(size_t)b * CAP + rstart[loc] + rk] = (int)(p & 0x00FFFFFFu);
    }
}

// ---------------------------------------------------------------- W pre-swizzle into MFMA B-fragment order
// Wf layout: frag f = (variant*4 + kstep)*CT + ct ; ushort offset f*512 + lane*8 + j
// value = W[k][n], k = kstep*32 + (lane>>4)*8 + j, n = ct*16 + (lane&15)
__global__ void k_wprep(const float* __restrict__ W, unsigned short* __restrict__ Wf,
                        int NOUT) {
    const int tid = blockIdx.x * 256 + threadIdx.x;
    const int CT = NOUT >> 4;
    const int total = 8 * CT * 64;
    if (tid >= total) return;
    const int lane = tid & 63;
    const int f = tid >> 6;
    const int v = f / (4 * CT);
    const int r = f - v * 4 * CT;
    const int s = r / CT;
    const int ct = r - s * CT;
    const int k0 = s * 32 + ((lane >> 4) << 3);
    const int n = (ct << 4) + (lane & 15);
    unsigned int pk[4];
#pragma unroll
    for (int jp = 0; jp < 4; ++jp) {
        unsigned int h2[2];
#pragma unroll
        for (int e = 0; e < 2; ++e) {
            int j = jp * 2 + e;
            float w = W[(size_t)(k0 + j) * NOUT + n];
            unsigned int hb = f2bf(w);
            if (v) hb = f2bf(w - bf2f_lo(hb));
            h2[e] = hb;
        }
        pk[jp] = h2[0] | (h2[1] << 16);
    }
    reinterpret_cast<uint4*>(Wf)[tid] = make_uint4(pk[0], pk[1], pk[2], pk[3]);
}

// ---------------------------------------------------------------- conv1 MFMA GEMM
// Hs1 = fp8_e4m3(dinv * x@W1), 3-term bf16 split on fp32 A.
__global__ __launch_bounds__(256, 2) void k_mgemm1(
    const float* __restrict__ A, const unsigned short* __restrict__ Wf,
    const float* __restrict__ dinv,
    unsigned char* __restrict__ Hs, int N) {
    constexpr int CT = 8;                 // 128/16
    constexpr int U4 = CT * 512;
    __shared__ uint4 WfL[U4];             // 64 KB
    for (int i = threadIdx.x; i < U4; i += 256)
        WfL[i] = reinterpret_cast<const uint4*>(Wf)[i];
    __syncthreads();

    const int lane = threadIdx.x & 63;
    const int kg = lane >> 4;
    const int lm = lane & 15;
    const int r0 = blockIdx.x * 64 + (threadIdx.x >> 6) * 16;
    const int arow = r0 + lm;

    s16x8 ah[4], al[4];
    const float4* A4 = reinterpret_cast<const float4*>(A);
#pragma unroll
    for (int s = 0; s < 4; ++s) {
        float4 p0 = make_float4(0.f, 0.f, 0.f, 0.f);
        float4 p1 = p0;
        if (arow < N) {
            p0 = A4[(size_t)arow * 32 + s * 8 + kg * 2];
            p1 = A4[(size_t)arow * 32 + s * 8 + kg * 2 + 1];
        }
        float vf[8] = {p0.x, p0.y, p0.z, p0.w, p1.x, p1.y, p1.z, p1.w};
#pragma unroll
        for (int j = 0; j < 8; ++j) {
            unsigned int hb = f2bf(vf[j]);
            ah[s][j] = (short)hb;
            al[s][j] = (short)f2bf(vf[j] - bf2f_lo(hb));
        }
    }

    float dv[4];
#pragma unroll
    for (int q = 0; q < 4; ++q) {
        int orow = r0 + kg * 4 + q;
        dv[q] = (orow < N) ? dinv[orow] : 0.f;
    }

    const unsigned short* LW = reinterpret_cast<const unsigned short*>(WfL);
#pragma unroll
    for (int ct = 0; ct < CT; ++ct) {
        f32x4 acc = {0.f, 0.f, 0.f, 0.f};
#pragma unroll
        for (int s = 0; s < 4; ++s) {
            s16x8 bh = *reinterpret_cast<const s16x8*>(LW + ((size_t)(s * CT + ct)) * 512 + lane * 8);
            s16x8 bl = *reinterpret_cast<const s16x8*>(LW + ((size_t)((4 + s) * CT + ct)) * 512 + lane * 8);
            acc = __builtin_amdgcn_mfma_f32_16x16x32_bf16(ah[s], bh, acc, 0, 0, 0);
            acc = __builtin_amdgcn_mfma_f32_16x16x32_bf16(al[s], bh, acc, 0, 0, 0);
            acc = __builtin_amdgcn_mfma_f32_16x16x32_bf16(ah[s], bl, acc, 0, 0, 0);
        }
        const int col = ct * 16 + lm;
#pragma unroll
        for (int q = 0; q < 4; ++q) {
            int orow = r0 + kg * 4 + q;
            if (orow < N)
                Hs[(size_t)orow * 128 + col] = f2fp8(dv[q] * acc[q]);
        }
    }
}

// ---------------------------------------------------------------- conv2 MFMA GEMM
// A = zp (relu'd bf16, exact) -> 2-term MFMA. Hs2 = bf16(dinv * zp@W2).
__global__ __launch_bounds__(256, 4) void k_mgemm2(
    const unsigned short* __restrict__ Z, const unsigned short* __restrict__ Wf,
    const float* __restrict__ dinv,
    unsigned short* __restrict__ Hs, int N) {
    constexpr int CT = 4;                 // 64/16
    constexpr int U4 = CT * 512;
    __shared__ uint4 WfL[U4];             // 32 KB
    for (int i = threadIdx.x; i < U4; i += 256)
        WfL[i] = reinterpret_cast<const uint4*>(Wf)[i];
    __syncthreads();

    const int lane = threadIdx.x & 63;
    const int kg = lane >> 4;
    const int lm = lane & 15;
    const int r0 = blockIdx.x * 64 + (threadIdx.x >> 6) * 16;
    const int arow = r0 + lm;

    s16x8 ah[4];
    const s16x8* Z8 = reinterpret_cast<const s16x8*>(Z);
#pragma unroll
    for (int s = 0; s < 4; ++s) {
        if (arow < N) ah[s] = Z8[(size_t)arow * 16 + s * 4 + kg];
        else          ah[s] = s16x8{0, 0, 0, 0, 0, 0, 0, 0};
    }

    float dv[4];
#pragma unroll
    for (int q = 0; q < 4; ++q) {
        int orow = r0 + kg * 4 + q;
        dv[q] = (orow < N) ? dinv[orow] : 0.f;
    }

    const unsigned short* LW = reinterpret_cast<const unsigned short*>(WfL);
#pragma unroll
    for (int ct = 0; ct < CT; ++ct) {
        f32x4 acc = {0.f, 0.f, 0.f, 0.f};
#pragma unroll
        for (int s = 0; s < 4; ++s) {
            s16x8 bh = *reinterpret_cast<const s16x8*>(LW + ((size_t)(s * CT + ct)) * 512 + lane * 8);
            s16x8 bl = *reinterpret_cast<const s16x8*>(LW + ((size_t)((4 + s) * CT + ct)) * 512 + lane * 8);
            acc = __builtin_amdgcn_mfma_f32_16x16x32_bf16(ah[s], bh, acc, 0, 0, 0);
            acc = __builtin_amdgcn_mfma_f32_16x16x32_bf16(ah[s], bl, acc, 0, 0, 0);
        }
        const int col = ct * 16 + lm;
#pragma unroll
        for (int q = 0; q < 4; ++q) {
            int orow = r0 + kg * 4 + q;
            if (orow < N)
                Hs[(size_t)orow * 64 + col] = (unsigned short)f2bf(dv[q] * acc[q]);
        }
    }
}

// ---------------------------------------------------------------- conv1 aggregate
// zp[node] = bf16(relu( dinv*( sum_j Hs1[src_j] + Hs1[node] ) + b1 ))
// Hs1 is fp8 [N][128]; LPG=8 threads/node, 16 ch each.
__global__ void k_gather1(const int* __restrict__ row_start, const int* __restrict__ row_end,
                          const int* __restrict__ csr_src,
                          const float* __restrict__ dinv,
                          const unsigned char* __restrict__ Hs,
                          const float* __restrict__ b1,
                          unsigned short* __restrict__ Zp, int N) {
    const int lane = threadIdx.x & 7;
    const int node = blockIdx.x * 32 + (threadIdx.x >> 3);
    if (node >= N) return;
    const int s0 = row_start[node];
    const int s1 = row_end[node];
    const float dn = dinv[node];
    const uint4* H = reinterpret_cast<const uint4*>(Hs);
    float acc[16];
#pragma unroll
    for (int i = 0; i < 16; ++i) acc[i] = 0.f;

    int j = s0;
    for (; j + 4 <= s1; j += 4) {
        int sa = csr_src[j], sb = csr_src[j + 1], sc = csr_src[j + 2], sd = csr_src[j + 3];
        uint4 ha = H[(size_t)sa * 8 + lane];
        uint4 hb = H[(size_t)sb * 8 + lane];
        uint4 hc = H[(size_t)sc * 8 + lane];
        uint4 hd = H[(size_t)sd * 8 + lane];
        fma16fp8(dn, ha, acc);
        fma16fp8(dn, hb, acc);
        fma16fp8(dn, hc, acc);
        fma16fp8(dn, hd, acc);
    }
    for (; j < s1; ++j) {
        uint4 h = H[(size_t)csr_src[j] * 8 + lane];
        fma16fp8(dn, h, acc);
    }
    {   // self-loop term
        uint4 h = H[(size_t)node * 8 + lane];
        fma16fp8(dn, h, acc);
    }

    const float4* B4 = reinterpret_cast<const float4*>(b1 + lane * 16);
    unsigned int pk[8];
#pragma unroll
    for (int p = 0; p < 4; ++p) {
        float4 b = B4[p];
        float f0 = fmaxf(acc[p * 4 + 0] + b.x, 0.f);
        float f1 = fmaxf(acc[p * 4 + 1] + b.y, 0.f);
        float f2 = fmaxf(acc[p * 4 + 2] + b.z, 0.f);
        float f3 = fmaxf(acc[p * 4 + 3] + b.w, 0.f);
        pk[p * 2]     = f2bf(f0) | (f2bf(f1) << 16);
        pk[p * 2 + 1] = f2bf(f2) | (f2bf(f3) << 16);
    }
    uint4* O = reinterpret_cast<uint4*>(Zp + (size_t)node * 128 + lane * 16);
    O[0] = make_uint4(pk[0], pk[1], pk[2], pk[3]);
    O[1] = make_uint4(pk[4], pk[5], pk[6], pk[7]);
}

// ---------------------------------------------------------------- conv2 aggregate
// out[node] = dinv*( sum_j Hs2[src_j] + Hs2[node] ) + b2   (fp32 write)
__global__ void k_gather2(const int* __restrict__ row_start, const int* __restrict__ row_end,
                          const int* __restrict__ csr_src,
                          const float* __restrict__ dinv,
                          const unsigned short* __restrict__ Hs,
                          const float* __restrict__ b2,
                          float* __restrict__ Out, int N) {
    const int lane = threadIdx.x & 7;
    const int node = blockIdx.x * 32 + (threadIdx.x >> 3);
    if (node >= N) return;
    const int s0 = row_start[node];
    const int s1 = row_end[node];
    const float dn = dinv[node];
    const uint4* H8 = reinterpret_cast<const uint4*>(Hs);
    float acc[8];
#pragma unroll
    for (int i = 0; i < 8; ++i) acc[i] = 0.f;

    int j = s0;
    for (; j + 4 <= s1; j += 4) {
        int sa = csr_src[j], sb = csr_src[j + 1], sc = csr_src[j + 2], sd = csr_src[j + 3];
        uint4 ha = H8[(size_t)sa * 8 + lane];
        uint4 hb = H8[(size_t)sb * 8 + lane];
        uint4 hc = H8[(size_t)sc * 8 + lane];
        uint4 hd = H8[(size_t)sd * 8 + lane];
        fma8(dn, ha, acc);
        fma8(dn, hb, acc);
        fma8(dn, hc, acc);
        fma8(dn, hd, acc);
    }
    for (; j < s1; ++j) {
        uint4 h = H8[(size_t)csr_src[j] * 8 + lane];
        fma8(dn, h, acc);
    }
    {   // self-loop term
        uint4 h = H8[(size_t)node * 8 + lane];
        fma8(dn, h, acc);
    }

    const float4* B4 = reinterpret_cast<const float4*>(b2 + lane * 8);
    float4 b0 = B4[0], b1v = B4[1];
    float4 o0, o1;
    o0.x = acc[0] + b0.x;  o0.y = acc[1] + b0.y;  o0.z = acc[2] + b0.z;  o0.w = acc[3] + b0.w;
    o1.x = acc[4] + b1v.x; o1.y = acc[5] + b1v.y; o1.z = acc[6] + b1v.z; o1.w = acc[7] + b1v.w;
    float4* O4 = reinterpret_cast<float4*>(Out + (size_t)node * 64 + lane * 8);
    O4[0] = o0; O4[1] = o1;
}

// ---------------------------------------------------------------- launch
extern "C" void kernel_launch(void* const* d_in, const int* in_sizes, int n_in,
                              void* d_out, int out_size, void* d_ws, size_t ws_size,
                              hipStream_t stream) {
    const float* x  = (const float*)d_in[0];
    const int*   ei = (const int*)d_in[1];
    const float* W1 = (const float*)d_in[2];
    const float* b1 = (const float*)d_in[3];
    const float* W2 = (const float*)d_in[4];
    const float* b2 = (const float*)d_in[5];
    float* out = (float*)d_out;

    const int N = in_sizes[0] / 128;
    const int E = in_sizes[1] / 2;
    const int* src = ei;       // edge_index[0]
    const int* dst = ei + E;   // edge_index[1]
    const int NB = (N + BUCKET_NODES - 1) >> BUCKET_SHIFT;

    char* ws = (char*)d_ws;
    size_t off = 0;
    auto alloc = [&](size_t bytes) -> char* {
        char* p = ws + off;
        off += (bytes + 255) & ~size_t(255);
        return p;
    };
    int*            bucket_cursor = (int*)alloc((size_t)MAXNB * 4);
    int*            row_start     = (int*)alloc((size_t)N * 4);
    int*            row_end       = (int*)alloc((size_t)N * 4);
    float*          dinv          = (float*)alloc((size_t)N * 4);
    unsigned int*   rec           = (unsigned int*)alloc((size_t)NB * CAP * 4);
    int*            csr_src       = (int*)alloc((size_t)NB * CAP * 4);
    unsigned char*  hs1           = (unsigned char*)alloc((size_t)N * 128);      // fp8
    unsigned short* hs2           = (unsigned short*)alloc((size_t)N * 64 * 2);  // bf16
    unsigned short* zp            = (unsigned short*)alloc((size_t)N * 128 * 2); // bf16 relu'd
    unsigned short* wf1           = (unsigned short*)alloc(128 * 128 * 2 * 2);   // 64 KB
    unsigned short* wf2           = (unsigned short*)alloc(128 * 64 * 2 * 2);    // 32 KB
    (void)ws_size; (void)n_in; (void)out_size;

    constexpr int EPT = 8;
    const int bin_blocks = (E + 256 * EPT - 1) / (256 * EPT);

    hipLaunchKernelGGL(k_zero, dim3((NB + 255) / 256), dim3(256), 0, stream,
                       bucket_cursor, NB);
    hipLaunchKernelGGL(k_wprep, dim3(16), dim3(256), 0, stream, W1, wf1, 128);
    hipLaunchKernelGGL(k_wprep, dim3(8), dim3(256), 0, stream, W2, wf2, 64);
    hipLaunchKernelGGL((k_bin<EPT>), dim3(bin_blocks), dim3(256), 0, stream,
                       src, dst, bucket_cursor, rec, E, NB);
    hipLaunchKernelGGL(k_degcsr, dim3(NB), dim3(256), 0, stream,
                       bucket_cursor, rec, csr_src, row_start, row_end, dinv, N);

    // conv1 GEMM: hs1 = fp8(dinv * x@W1)
    hipLaunchKernelGGL(k_mgemm1, dim3((N + 63) / 64), dim3(256), 0, stream,
                       x, wf1, dinv, hs1, N);

    // conv1 aggregate: zp = bf16(relu(msgs + self + b1))
    hipLaunchKernelGGL(k_gather1, dim3((N + 31) / 32), dim3(256), 0, stream,
                       row_start, row_end, csr_src, dinv, hs1, b1, zp, N);

    // conv2 GEMM: hs2 = bf16(dinv * zp@W2)
    hipLaunchKernelGGL(k_mgemm2, dim3((N + 63) / 64), dim3(256), 0, stream,
                       zp, wf2, dinv, hs2, N);

    // conv2 aggregate: out = msgs + self + b2
    hipLaunchKernelGGL(k_gather2, dim3((N + 31) / 32), dim3(256), 0, stream,
                       row_start, row_end, csr_src, dinv, hs2, b2, out, N);
}